// Round 2
// baseline (248.210 us; speedup 1.0000x reference)
//
#include <hip/hip_runtime.h>

// Problem constants
#define BB 32      // batch
#define CC 16      // channels
#define TT 16384   // time
#define PP 32      // taps
#define NNA 33     // N = p+1
#define STRIDE 36  // LDS row stride (floats), 16B-aligned, breaks write conflicts

// ws layout (floats), parameterized by K (number of chunks, LL = TT/K):
//   H_T : [C*K][32 i][32 j]   (homogeneous tails, transposed: row i contig over j)
//   Yp  : [C*K][32 b][32 i]   (particular tails)
//   Ss  : [C*K][32 b][32 i]   (chunk start states)

// ---------------------------------------------------------------------------
// stage normalized taps: lds[r*STRIDE + (j-1)] = A[c][j][t0+r] / A[c][0][t0+r]
// ---------------------------------------------------------------------------
template <int ROWS>
__device__ __forceinline__ void stage_coefs(const float* __restrict__ Ac,
                                            float* __restrict__ lds, int lane) {
    float r0[ROWS / 64];
#pragma unroll
    for (int m = 0; m < ROWS / 64; ++m)
        r0[m] = 1.0f / Ac[lane + 64 * m];
#pragma unroll
    for (int j = 1; j <= PP; ++j) {
#pragma unroll
        for (int m = 0; m < ROWS / 64; ++m) {
            lds[(lane + 64 * m) * STRIDE + (j - 1)] =
                Ac[(size_t)j * TT + lane + 64 * m] * r0[m];
        }
    }
}

// one IIR step; s must be compile-time constant (unrolled callers), ring phase 0
__device__ __forceinline__ float iir_step(const float* __restrict__ row,
                                          const float hist[32], float x, int s) {
    const float4* cp = reinterpret_cast<const float4*>(row);
    float cf[32];
#pragma unroll
    for (int q = 0; q < 8; ++q) {
        float4 v = cp[q];
        cf[4 * q + 0] = v.x; cf[4 * q + 1] = v.y;
        cf[4 * q + 2] = v.z; cf[4 * q + 3] = v.w;
    }
    float a0 = 0.f, a1 = 0.f, a2 = 0.f, a3 = 0.f;
#pragma unroll
    for (int j = 2; j <= 32; ++j) {
        float t = cf[j - 1] * hist[(s - j) & 31];
        if ((j & 3) == 0) a0 += t;
        else if ((j & 3) == 1) a1 += t;
        else if ((j & 3) == 2) a2 += t;
        else a3 += t;
    }
    return x - ((a0 + a1) + (a2 + a3)) - cf[0] * hist[(s - 1) & 31];
}

// ---------------------------------------------------------------------------
// Kernel A: per (c,chunk): lanes 0-31 particular (per batch), 32-63 homogeneous.
// Writes Yp tails (b-major) and H tails transposed (i-major).
// ---------------------------------------------------------------------------
template <int K>
__global__ __launch_bounds__(64, 4)
void kA(const float* __restrict__ X, const float* __restrict__ A,
        float* __restrict__ ws) {
    constexpr int LL = TT / K;
    __shared__ __align__(16) float lds[LL * STRIDE];
    const int bid  = blockIdx.x;
    const int c    = bid / K;
    const int k    = bid % K;
    const int lane = threadIdx.x;
    const int t0   = k * LL;

    stage_coefs<LL>(A + (size_t)c * NNA * TT + t0, lds, lane);
    __syncthreads();

    float hist[32];
#pragma unroll
    for (int i2 = 0; i2 < 32; ++i2)
        hist[i2] = (lane == 32 + i2) ? 1.0f : 0.0f;

    const int  b   = lane & 31;
    const bool isx = (lane < 32);
    const float* xrow = X + ((size_t)b * CC + c) * TT + t0;

#pragma unroll 1
    for (int g = 0; g < LL / 32; ++g) {
        float xv[32];
        if (isx) {
            const float4* xp = reinterpret_cast<const float4*>(xrow + g * 32);
#pragma unroll
            for (int q = 0; q < 8; ++q) {
                float4 v = xp[q];
                xv[4 * q + 0] = v.x; xv[4 * q + 1] = v.y;
                xv[4 * q + 2] = v.z; xv[4 * q + 3] = v.w;
            }
        } else {
#pragma unroll
            for (int q = 0; q < 32; ++q) xv[q] = 0.0f;
        }
#pragma unroll
        for (int s = 0; s < 32; ++s) {
            float y = iir_step(&lds[(g * 32 + s) * STRIDE], hist, xv[s], s);
            hist[s & 31] = y;
        }
    }

    // tails: hist[i] = y[t0+LL-32+i]
    float* wsH  = ws;
    float* wsYp = ws + (size_t)CC * K * 1024;
    const size_t base = ((size_t)c * K + k) * 1024;
    if (lane < 32) {
        float4* dst = reinterpret_cast<float4*>(wsYp + base + (size_t)lane * 32);
#pragma unroll
        for (int q = 0; q < 8; ++q) {
            float4 v = {hist[4 * q + 0], hist[4 * q + 1],
                        hist[4 * q + 2], hist[4 * q + 3]};
            dst[q] = v;
        }
    } else {
        const int j = lane - 32;
#pragma unroll
        for (int i2 = 0; i2 < 32; ++i2)
            wsH[base + (size_t)i2 * 32 + j] = hist[i2];
    }
}

// ---------------------------------------------------------------------------
// Kernel B: sequential chunk chaining, half-wave per (b,c) pair, lane = comp i.
// s_{k+1}[i] = Yp[k][b][i] + sum_j H_T[k][i][j] * s_k[j]; ping-pong prefetch.
// ---------------------------------------------------------------------------
template <int K>
__global__ __launch_bounds__(64)
void kB(float* __restrict__ ws) {
    const int lane = threadIdx.x;
    const int i    = lane & 31;
    const int pair = blockIdx.x * 2 + (lane >> 5);
    const int c    = pair >> 5;
    const int b    = pair & 31;

    const float* __restrict__ H  = ws;
    const float* __restrict__ Yp = ws + (size_t)CC * K * 1024;
    float* __restrict__ Ss       = ws + (size_t)2 * CC * K * 1024;
    const size_t cb = (size_t)c * K;

    float hA[32], hB[32];
    float ypA = 0.f, ypB = 0.f;

#define LOAD_HK(kk, harr, ypv)                                                  \
    {                                                                           \
        const float4* p = reinterpret_cast<const float4*>(                      \
            H + ((cb + (kk)) * 32 + i) * 32);                                   \
        _Pragma("unroll")                                                       \
        for (int u = 0; u < 8; ++u) {                                           \
            float4 v = p[u];                                                    \
            harr[4 * u + 0] = v.x; harr[4 * u + 1] = v.y;                       \
            harr[4 * u + 2] = v.z; harr[4 * u + 3] = v.w;                       \
        }                                                                       \
        ypv = Yp[((cb + (kk)) * 32 + b) * 32 + i];                              \
    }

#define STEP_K(kk, harr, ypv)                                                   \
    {                                                                           \
        Ss[((cb + (kk)) * 32 + b) * 32 + i] = sv;                               \
        float a0 = 0.f, a1 = 0.f, a2 = 0.f, a3 = 0.f;                           \
        _Pragma("unroll")                                                       \
        for (int j = 0; j < 32; ++j) {                                          \
            float sb = __shfl(sv, (lane & 32) + j, 64);                         \
            float t  = harr[j] * sb;                                            \
            if ((j & 3) == 0) a0 += t;                                          \
            else if ((j & 3) == 1) a1 += t;                                     \
            else if ((j & 3) == 2) a2 += t;                                     \
            else a3 += t;                                                       \
        }                                                                       \
        sv = ypv + ((a0 + a1) + (a2 + a3));                                     \
    }

    float sv = 0.0f;
    LOAD_HK(0, hA, ypA);
#pragma unroll 1
    for (int k = 0; k < K; k += 2) {
        if (k + 1 < K) LOAD_HK(k + 1, hB, ypB);
        STEP_K(k, hA, ypA);
        if (k + 2 < K) LOAD_HK(k + 2, hA, ypA);
        STEP_K(k + 1, hB, ypB);
    }
#undef LOAD_HK
#undef STEP_K
}

// ---------------------------------------------------------------------------
// Kernel C: final pass. Each block = one super-chunk (two LL-chunks), half-wave
// per chunk: lane = b + 32*half. All 64 lanes productive.
// ---------------------------------------------------------------------------
template <int K>
__global__ __launch_bounds__(64, 2)
void kC(const float* __restrict__ X, const float* __restrict__ A,
        const float* __restrict__ ws, float* __restrict__ Y) {
    constexpr int LL = TT / K;
    constexpr int R2 = 2 * LL;
    __shared__ __align__(16) float lds[R2 * STRIDE];
    const int bid  = blockIdx.x;
    const int c    = bid / (K / 2);
    const int m    = bid % (K / 2);
    const int lane = threadIdx.x;
    const int t0   = m * R2;

    stage_coefs<R2>(A + (size_t)c * NNA * TT + t0, lds, lane);
    __syncthreads();

    const int half = lane >> 5;
    const int b    = lane & 31;
    const int k    = 2 * m + half;

    const float* Ss = ws + (size_t)2 * CC * K * 1024;
    const size_t base = ((size_t)c * K + k) * 1024;

    float hist[32];
    {
        const float4* sp = reinterpret_cast<const float4*>(Ss + base + (size_t)b * 32);
#pragma unroll
        for (int q = 0; q < 8; ++q) {
            float4 v = sp[q];
            hist[4 * q + 0] = v.x; hist[4 * q + 1] = v.y;
            hist[4 * q + 2] = v.z; hist[4 * q + 3] = v.w;
        }
    }

    const float* xrow = X + ((size_t)b * CC + c) * TT + t0 + half * LL;
    float*       yrow = Y + ((size_t)b * CC + c) * TT + t0 + half * LL;
    const float* ldsh = lds + (size_t)(half * LL) * STRIDE;

#pragma unroll 1
    for (int g = 0; g < LL / 32; ++g) {
        float xv[32];
        const float4* xp = reinterpret_cast<const float4*>(xrow + g * 32);
#pragma unroll
        for (int q = 0; q < 8; ++q) {
            float4 v = xp[q];
            xv[4 * q + 0] = v.x; xv[4 * q + 1] = v.y;
            xv[4 * q + 2] = v.z; xv[4 * q + 3] = v.w;
        }
#pragma unroll
        for (int s = 0; s < 32; ++s) {
            float y = iir_step(&ldsh[(g * 32 + s) * STRIDE], hist, xv[s], s);
            hist[s & 31] = y;
            xv[s] = y;
        }
        float4* yp4 = reinterpret_cast<float4*>(yrow + g * 32);
#pragma unroll
        for (int q = 0; q < 8; ++q) {
            float4 v = {xv[4 * q + 0], xv[4 * q + 1],
                        xv[4 * q + 2], xv[4 * q + 3]};
            yp4[q] = v;
        }
    }
}

template <int K>
static void launch_all(const float* X, const float* A, float* Y, float* ws,
                       hipStream_t stream) {
    kA<K><<<CC * K, 64, 0, stream>>>(X, A, ws);
    kB<K><<<(BB * CC) / 2, 64, 0, stream>>>(ws);
    kC<K><<<CC * K / 2, 64, 0, stream>>>(X, A, ws, Y);
}

extern "C" void kernel_launch(void* const* d_in, const int* in_sizes, int n_in,
                              void* d_out, int out_size, void* d_ws, size_t ws_size,
                              hipStream_t stream) {
    const float* X = (const float*)d_in[0];   // (B,C,T)
    const float* A = (const float*)d_in[1];   // (C,N,T)
    float* Y  = (float*)d_out;
    float* ws = (float*)d_ws;

    auto need = [](size_t K) { return (size_t)3 * CC * K * 1024 * 4; };
    if (ws_size >= need(256))      launch_all<256>(X, A, Y, ws, stream);
    else if (ws_size >= need(128)) launch_all<128>(X, A, Y, ws, stream);
    else                           launch_all<64>(X, A, Y, ws, stream);
}